// Round 17
// baseline (7179.762 us; speedup 1.0000x reference)
//
#include <hip/hip_runtime.h>
#include <hip/hip_bf16.h>

#define TT 2048
#define BB 256
#define HH 128
#define UDIM 16
#define YDIM 16
#define ZDIM 32
#define H3 384

typedef __hip_bfloat16 bf16;
typedef _Float16 half2v __attribute__((ext_vector_type(2)));

constexpr int clog2(int x) { return x <= 1 ? 0 : 1 + clog2(x >> 1); }

// ---------------------------------------------------------------------------
// f32 register-weight linear stage (phi_u only).
// ---------------------------------------------------------------------------
template <int M_, int K_, int O_, bool RELU_>
__device__ __forceinline__ void rstage(const float* __restrict__ wfrag,
                                       const float* __restrict__ xin, int XS,
                                       float* __restrict__ ps,
                                       const float* __restrict__ bias,
                                       float* __restrict__ outb)
{
    constexpr int F = K_ / O_;
    const int T = threadIdx.x;
    const int jb = T & (M_ / 2 - 1);
    const int o  = T >> clog2(M_ / 2);
#pragma unroll
    for (int r = 0; r < 8; ++r) {
        float a0 = 0.f, a1 = 0.f;
#pragma unroll
        for (int g = 0; g < F; g += 4) {
            const float4 xv = *reinterpret_cast<const float4*>(&xin[r * XS + o * F + g]);
            a0 += xv.x * wfrag[g]     + xv.y * wfrag[g + 1]
                + xv.z * wfrag[g + 2] + xv.w * wfrag[g + 3];
            a1 += xv.x * wfrag[F + g]     + xv.y * wfrag[F + g + 1]
                + xv.z * wfrag[F + g + 2] + xv.w * wfrag[F + g + 3];
        }
        ps[r * 1024 + o * M_ + jb]           = a0;
        ps[r * 1024 + o * M_ + jb + M_ / 2]  = a1;
    }
    __syncthreads();
    for (int oi = T; oi < 8 * M_; oi += 512) {
        const int r = oi >> clog2(M_);
        const int j = oi & (M_ - 1);
        float s = bias[j];
#pragma unroll
        for (int o2 = 0; o2 < O_; ++o2) s += ps[r * 1024 + o2 * M_ + j];
        if (RELU_) s = fmaxf(s, 0.f);
        outb[r * M_ + j] = s;
    }
    __syncthreads();
}

template <int M_, int K_, int O_>
__device__ __forceinline__ void loadw(float* __restrict__ wfrag, const float* __restrict__ Wg)
{
    constexpr int F = K_ / O_;
    const int T = threadIdx.x;
    const int jb = T & (M_ / 2 - 1);
    const int o  = T >> clog2(M_ / 2);
#pragma unroll
    for (int h = 0; h < 2; ++h)
#pragma unroll
        for (int g = 0; g < F; g += 4)
            *reinterpret_cast<float4*>(&wfrag[h * F + g]) =
                *reinterpret_cast<const float4*>(&Wg[(jb + h * (M_ / 2)) * K_ + o * F + g]);
}

// f16 variants (head): wfrag = F half2 (2 rows x F/2), xin f16 LDS, XS in halves.
template <int M_, int K_, int O_>
__device__ __forceinline__ void loadw_h(half2v* __restrict__ wfrag, const float* __restrict__ Wg)
{
    constexpr int F = K_ / O_;
    const int T = threadIdx.x;
    const int jb = T & (M_ / 2 - 1);
    const int o  = T >> clog2(M_ / 2);
#pragma unroll
    for (int h = 0; h < 2; ++h)
#pragma unroll
        for (int g = 0; g < F / 2; ++g) {
            const float* s = &Wg[(jb + h * (M_ / 2)) * K_ + o * F + 2 * g];
            half2v v; v.x = (_Float16)s[0]; v.y = (_Float16)s[1];
            wfrag[h * (F / 2) + g] = v;
        }
}

template <int M_, int K_, int O_, bool RELU_>
__device__ __forceinline__ void rstage_h(const half2v* __restrict__ wfrag,
                                         const _Float16* __restrict__ xin, int XS,
                                         float* __restrict__ ps,
                                         const float* __restrict__ bias,
                                         _Float16* __restrict__ outb)
{
    constexpr int F = K_ / O_;
    constexpr int FH = F / 2;
    const int T = threadIdx.x;
    const int jb = T & (M_ / 2 - 1);
    const int o  = T >> clog2(M_ / 2);
#pragma unroll
    for (int r = 0; r < 8; ++r) {
        float a0 = 0.f, a1 = 0.f;
        const half2v* xv = reinterpret_cast<const half2v*>(xin + r * XS + o * F);
        if constexpr (FH >= 4) {
#pragma unroll
            for (int g4 = 0; g4 < FH / 4; ++g4) {
                half2v xt[4];
                *reinterpret_cast<float4*>(xt) = reinterpret_cast<const float4*>(xv)[g4];
#pragma unroll
                for (int e = 0; e < 4; ++e) {
                    a0 = __builtin_amdgcn_fdot2(xt[e], wfrag[g4 * 4 + e], a0, false);
                    a1 = __builtin_amdgcn_fdot2(xt[e], wfrag[FH + g4 * 4 + e], a1, false);
                }
            }
        } else {   // FH == 2
            half2v xt[2];
            *reinterpret_cast<float2*>(xt) = *reinterpret_cast<const float2*>(xv);
            a0 = __builtin_amdgcn_fdot2(xt[0], wfrag[0], a0, false);
            a0 = __builtin_amdgcn_fdot2(xt[1], wfrag[1], a0, false);
            a1 = __builtin_amdgcn_fdot2(xt[0], wfrag[FH], a1, false);
            a1 = __builtin_amdgcn_fdot2(xt[1], wfrag[FH + 1], a1, false);
        }
        ps[r * 1024 + o * M_ + jb]           = a0;
        ps[r * 1024 + o * M_ + jb + M_ / 2]  = a1;
    }
    __syncthreads();
    for (int oi = T; oi < 8 * M_; oi += 512) {
        const int r = oi >> clog2(M_);
        const int j = oi & (M_ - 1);
        float s = bias[j];
#pragma unroll
        for (int o2 = 0; o2 < O_; ++o2) s += ps[r * 1024 + o2 * M_ + j];
        if (RELU_) s = fmaxf(s, 0.f);
        outb[r * M_ + j] = (_Float16)s;
    }
    __syncthreads();
}

// ---------------------------------------------------------------------------
// Head-weight composition precompute (exact linear algebra):
//   A   = pxw1 (128x32) · xw (32x128)                     -> (128x128)
//   W_C = A · dw2 (128x128)                               -> (128x128)
//   b_C = A · db2 + pxw1 · xb + pxb1                      -> (128)
// Merges head stages S2,S3,S4 into one 128x128 stage.
// ---------------------------------------------------------------------------
__global__ __launch_bounds__(512) void pre1_kernel(
    const float* __restrict__ pxw1, const float* __restrict__ xw, float* __restrict__ A)
{
    const int T = threadIdx.x;
    for (int idx = T; idx < 128 * 128; idx += 512) {
        const int j = idx >> 7, m = idx & 127;
        float s = 0.f;
#pragma unroll
        for (int z = 0; z < 32; ++z) s += pxw1[j * 32 + z] * xw[z * 128 + m];
        A[idx] = s;
    }
}

__global__ __launch_bounds__(512) void pre2_kernel(
    const float* __restrict__ A, const float* __restrict__ dw2,
    const float* __restrict__ db2, const float* __restrict__ pxw1,
    const float* __restrict__ xb, const float* __restrict__ pxb1,
    float* __restrict__ wC, float* __restrict__ bC)
{
    const int idx = blockIdx.x * 512 + threadIdx.x;
    if (blockIdx.x < 32) {
        const int j = idx >> 7, k = idx & 127;
        float s = 0.f;
        for (int m = 0; m < 128; ++m) s += A[j * 128 + m] * dw2[m * 128 + k];
        wC[idx] = s;
    } else if (threadIdx.x < 128) {
        const int j = threadIdx.x;
        float s = pxb1[j];
        for (int m = 0; m < 128; ++m) s += A[j * 128 + m] * db2[m];
#pragma unroll
        for (int z = 0; z < 32; ++z) s += pxw1[j * 32 + z] * xb[z];
        bC[j] = s;
    }
}

// ---------------------------------------------------------------------------
// phi_u: register weights, persistent 512 blocks (unchanged).
// ---------------------------------------------------------------------------
__global__ __launch_bounds__(512, 2) void phi_u_kernel(
    const float* __restrict__ u, const float* __restrict__ w1, const float* __restrict__ b1,
    const float* __restrict__ w2, const float* __restrict__ b2,
    bf16* __restrict__ pu, int s0, int nrows)
{
    __shared__ __align__(16) float ps[8192];
    __shared__ __align__(16) float xc[8 * 16];
    __shared__ __align__(16) float bP[8 * 128];
    __shared__ __align__(16) float bias_l[256];
    const int T = threadIdx.x;
    if (T < 128) { bias_l[T] = b1[T]; bias_l[128 + T] = b2[T]; }
    const int jb = T & 63, o = T >> 6;
    float wa[4];
    wa[0] = w1[jb * 16 + o * 2];        wa[1] = w1[jb * 16 + o * 2 + 1];
    wa[2] = w1[(jb + 64) * 16 + o * 2]; wa[3] = w1[(jb + 64) * 16 + o * 2 + 1];
    float wb[32]; loadw<128, 128, 8>(wb, w2);
    __syncthreads();

    for (int tile = blockIdx.x; tile < nrows / 32; tile += gridDim.x) {
        const int n0 = tile * 32;
        const int b  = s0 + (n0 >> 11);
        const int t0 = n0 & (TT - 1);
#pragma unroll 1
        for (int rb = 0; rb < 4; ++rb) {
            if (T < 128) {
                const int r = T & 7, c = T >> 3;
                xc[r * 16 + c] = u[((size_t)b * UDIM + c) * TT + t0 + rb * 8 + r];
            }
            __syncthreads();
#pragma unroll
            for (int r = 0; r < 8; ++r) {
                const float x0 = xc[r * 16 + o * 2], x1 = xc[r * 16 + o * 2 + 1];
                ps[r * 1024 + o * 128 + jb]      = x0 * wa[0] + x1 * wa[1];
                ps[r * 1024 + o * 128 + jb + 64] = x0 * wa[2] + x1 * wa[3];
            }
            __syncthreads();
            for (int oi = T; oi < 8 * 128; oi += 512) {
                const int r = oi >> 7, j = oi & 127;
                float s = bias_l[j];
#pragma unroll
                for (int o2 = 0; o2 < 8; ++o2) s += ps[r * 1024 + o2 * 128 + j];
                bP[r * 128 + j] = fmaxf(s, 0.f);
            }
            __syncthreads();
            rstage<128, 128, 8, false>(wb, bP, 128, ps, bias_l + 128, bP);
            const int row0 = n0 + rb * 8;
            for (int oi = T; oi < 8 * 128; oi += 512) {
                const int r = oi >> 7, j = oi & 127;
                pu[(size_t)(row0 + r) * HH + j] = __float2bfloat16(bP[r * 128 + j]);
            }
            __syncthreads();
        }
    }
}

// ---------------------------------------------------------------------------
// Fused 2-layer GRU, 512 threads (round-12 proven config).
// ---------------------------------------------------------------------------
__device__ __forceinline__ void gmv(const half2v w[6][16], const _Float16* __restrict__ vb,
                                    int o, float* __restrict__ psL, int psb)
{
    const half2v* vec2 = reinterpret_cast<const half2v*>(vb) + o * 16;
    float a0 = 0.f, a1 = 0.f, a2 = 0.f, a3 = 0.f, a4 = 0.f, a5 = 0.f;
#pragma unroll
    for (int k4 = 0; k4 < 4; ++k4) {
        half2v xt[4];
        *reinterpret_cast<float4*>(xt) = reinterpret_cast<const float4*>(vec2)[k4];
#pragma unroll
        for (int e = 0; e < 4; ++e) {
            const int k = k4 * 4 + e;
            a0 = __builtin_amdgcn_fdot2(xt[e], w[0][k], a0, false);
            a1 = __builtin_amdgcn_fdot2(xt[e], w[1][k], a1, false);
            a2 = __builtin_amdgcn_fdot2(xt[e], w[2][k], a2, false);
            a3 = __builtin_amdgcn_fdot2(xt[e], w[3][k], a3, false);
            a4 = __builtin_amdgcn_fdot2(xt[e], w[4][k], a4, false);
            a5 = __builtin_amdgcn_fdot2(xt[e], w[5][k], a5, false);
        }
    }
    psL[psb]       = a0; psL[psb + 64]  = a1; psL[psb + 128] = a2;
    psL[psb + 192] = a3; psL[psb + 256] = a4; psL[psb + 320] = a5;
}

__global__ __launch_bounds__(512, 2) void gru_fused_kernel(
    const bf16* __restrict__ pu_in,   // (C*T, H)
    const float* __restrict__ wih,    // (L, 3H, H)
    const float* __restrict__ whh,    // (L, 3H, H)
    const float* __restrict__ h0_g,   // (L, B, H)
    bf16* __restrict__ hlast,         // (C*T, H)
    int s0)
{
    const int t = threadIdx.x;
    __shared__ __align__(16) _Float16 x0h[HH];
    __shared__ __align__(16) _Float16 x1h[2][HH];
    __shared__ __align__(16) _Float16 h0h[HH];
    __shared__ __align__(16) _Float16 h1h[HH];
    __shared__ __align__(16) float ps[2 * 3072];

    const int g = t >> 6;             // wave-uniform
    const int m = g >> 2, o = g & 3;
    const int u = t & 63;
    const float* WbaseA = ((m == 0) ? wih : whh);
    const float* WbaseB = WbaseA + (size_t)H3 * HH;
    half2v wA[6][16], wB[6][16];
#pragma unroll
    for (int i = 0; i < 6; ++i) {
        const float* sA = &WbaseA[(u + 64 * i) * HH + o * 32];
        const float* sB = &WbaseB[(u + 64 * i) * HH + o * 32];
#pragma unroll
        for (int k = 0; k < 16; ++k) {
            half2v v; v.x = (_Float16)sA[2 * k]; v.y = (_Float16)sA[2 * k + 1];
            wA[i][k] = v;
            half2v w2; w2.x = (_Float16)sB[2 * k]; w2.y = (_Float16)sB[2 * k + 1];
            wB[i][k] = w2;
        }
    }
    float* psA = ps;
    float* psB = ps + 3072;
    const int psb = o * 768 + m * 384 + u;

    const bf16* xb = pu_in + (size_t)blockIdx.x * TT * HH;
    bf16* ob = hlast + (size_t)blockIdx.x * TT * HH;

    float hreg = 0.f;                 // t<128: L0 state; t in [128,256): L1 state
    if (t < HH) {
        hreg = h0_g[(size_t)(s0 + blockIdx.x) * HH + t];
        h0h[t] = (_Float16)hreg;
        x0h[t] = (_Float16)__bfloat162float(xb[t]);
    } else if (t < 2 * HH) {
        const int j = t - HH;
        hreg = h0_g[((size_t)BB + s0 + blockIdx.x) * HH + j];
        h1h[j] = (_Float16)hreg;
    }
    __syncthreads();

#pragma unroll 1
    for (int i = 0; i <= TT; ++i) {
        float xnext = 0.f;
        if (t < HH && i + 1 < TT)
            xnext = __bfloat162float(xb[(size_t)(i + 1) * HH + t]);   // prefetch for L0
        if (i < TT)  gmv(wA, (m == 0) ? x0h : h0h, o, psA, psb);
        if (i >= 1)  gmv(wB, (m == 0) ? x1h[(i + 1) & 1] : h1h, o, psB, psb);
        __syncthreads();   // ps ready; all LDS vec reads done
        if (t < HH) {
            if (i < TT) {
                const int j = t;
                float gir = 0.f, giz = 0.f, gin = 0.f, ghr = 0.f, ghz = 0.f, ghn = 0.f;
#pragma unroll
                for (int o2 = 0; o2 < 4; ++o2) {
                    const float* pp = psA + o2 * 768;
                    gir += pp[j];        giz += pp[128 + j]; gin += pp[256 + j];
                    ghr += pp[384 + j];  ghz += pp[512 + j]; ghn += pp[640 + j];
                }
                const float rg = 1.f / (1.f + __expf(-(gir + ghr)));
                const float zg = 1.f / (1.f + __expf(-(giz + ghz)));
                const float narg = gin + rg * ghn;
                const float e2 = __expf(2.f * fabsf(narg));
                float ng = 1.f - 2.f / (e2 + 1.f);
                ng = (narg < 0.f) ? -ng : ng;
                const float hn = (1.f - zg) * ng + zg * hreg;
                h0h[j] = (_Float16)hn;
                x1h[i & 1][j] = (_Float16)hn;   // L1 input for step i
                x0h[j] = (_Float16)xnext;
                hreg = hn;
            }
        } else if (t < 2 * HH) {
            if (i >= 1) {
                const int j = t - HH;
                float gir = 0.f, giz = 0.f, gin = 0.f, ghr = 0.f, ghz = 0.f, ghn = 0.f;
#pragma unroll
                for (int o2 = 0; o2 < 4; ++o2) {
                    const float* pp = psB + o2 * 768;
                    gir += pp[j];        giz += pp[128 + j]; gin += pp[256 + j];
                    ghr += pp[384 + j];  ghz += pp[512 + j]; ghn += pp[640 + j];
                }
                const float rg = 1.f / (1.f + __expf(-(gir + ghr)));
                const float zg = 1.f / (1.f + __expf(-(giz + ghz)));
                const float narg = gin + rg * ghn;
                const float e2 = __expf(2.f * fabsf(narg));
                float ng = 1.f - 2.f / (e2 + 1.f);
                ng = (narg < 0.f) ? -ng : ng;
                ob[(size_t)(i - 1) * HH + j] = __float2bfloat16(hreg);  // pre-update
                const float hn = (1.f - zg) * ng + zg * hreg;
                h1h[j] = (_Float16)hn;
                hreg = hn;
            }
        }
        __syncthreads();   // h/x updated for next iteration
    }
}

// ---------------------------------------------------------------------------
// head v5: composed stages — S1 (256->128 relu), SC (composite 128->128 relu),
// S5 (128->128), S6 (128->128 relu), S7 (128->16 + loss). 5 stages, 10
// barriers per 8-row batch (was 7 stages / 14 barriers).
// ---------------------------------------------------------------------------
__device__ __forceinline__ void stage_xc_h(_Float16* __restrict__ xc,
                                           const bf16* __restrict__ pu,
                                           const bf16* __restrict__ hl,
                                           int n0, int rb)
{
    const int T = threadIdx.x;
    const int base = n0 + rb * 8;
#pragma unroll
    for (int i = 0; i < 4; ++i) {
        const int idx = T + i * 512;
        const int r = idx >> 8, k = idx & 255;
        const size_t row = (size_t)(base + r);
        xc[r * 256 + k] = (_Float16)((k < 128) ? __bfloat162float(pu[row * HH + k])
                                               : __bfloat162float(hl[row * HH + (k - 128)]));
    }
}

__global__ __launch_bounds__(512, 2) void head_kernel(
    const bf16* __restrict__ pu, const bf16* __restrict__ hlast, const float* __restrict__ y_g,
    const float* __restrict__ dw1, const float* __restrict__ db1,
    const float* __restrict__ wC, const float* __restrict__ bC,
    const float* __restrict__ pxw2, const float* __restrict__ pxb2,
    const float* __restrict__ mw1, const float* __restrict__ mb1,
    const float* __restrict__ mw2, const float* __restrict__ mb2,
    float* __restrict__ out, int s0, int nrows)
{
    __shared__ __align__(16) float ps[8192];
    __shared__ __align__(16) _Float16 xc[8 * 256];
    __shared__ __align__(16) _Float16 bP[8 * 128];
    __shared__ __align__(16) _Float16 bQ[8 * 128];
    __shared__ __align__(16) float bias_l[528];
    __shared__ float red[8];
    const int T = threadIdx.x;

    if (T < 128) bias_l[T]       = db1[T];
    if (T < 128) bias_l[128 + T] = bC[T];
    if (T < 128) bias_l[256 + T] = pxb2[T];
    if (T < 128) bias_l[384 + T] = mb1[T];
    if (T < 16)  bias_l[512 + T] = mb2[T];

    half2v w1[32]; loadw_h<128, 256, 8 >(w1, dw1);
    half2v wc[16]; loadw_h<128, 128, 8 >(wc, wC);
    half2v w5[16]; loadw_h<128, 128, 8 >(w5, pxw2);
    half2v w6[16]; loadw_h<128, 128, 8 >(w6, mw1);
    const int jb7 = T & 7, o7 = T >> 3;   // S7: M=16,K=128,O=64,F=2
    half2v w7a, w7b;
    w7a.x = (_Float16)mw2[jb7 * 128 + 2 * o7];
    w7a.y = (_Float16)mw2[jb7 * 128 + 2 * o7 + 1];
    w7b.x = (_Float16)mw2[(jb7 + 8) * 128 + 2 * o7];
    w7b.y = (_Float16)mw2[(jb7 + 8) * 128 + 2 * o7 + 1];

    float lossreg = 0.f;

    for (int tile = blockIdx.x; tile < nrows / 32; tile += gridDim.x) {
        const int n0 = tile * 32;
        const int b  = s0 + (n0 >> 11);
        const int t0 = n0 & (TT - 1);
        stage_xc_h(xc, pu, hlast, n0, 0);
#pragma unroll 1
        for (int rb = 0; rb < 4; ++rb) {
            __syncthreads();   // xc ready; ps free from previous batch
            rstage_h<128, 256, 8, true >(w1, xc, 256, ps, bias_l + 0,   bP);  // dynn hid
            rstage_h<128, 128, 8, true >(wc, bP, 128, ps, bias_l + 128, bQ);  // composite
            rstage_h<128, 128, 8, false>(w5, bQ, 128, ps, bias_l + 256, bP);  // px
            rstage_h<128, 128, 8, true >(w6, bP, 128, ps, bias_l + 384, bQ);  // menn hid
            // S7 partials (dot2) + prefetch next batch's xc
#pragma unroll
            for (int r = 0; r < 8; ++r) {
                const half2v xv = *reinterpret_cast<const half2v*>(&bQ[r * 128 + 2 * o7]);
                ps[r * 1024 + o7 * 16 + jb7]     = __builtin_amdgcn_fdot2(xv, w7a, 0.f, false);
                ps[r * 1024 + o7 * 16 + jb7 + 8] = __builtin_amdgcn_fdot2(xv, w7b, 0.f, false);
            }
            if (rb < 3) stage_xc_h(xc, pu, hlast, n0, rb + 1);
            __syncthreads();
            if (T < 128) {
                const int r = T >> 4, j = T & 15;
                float s = bias_l[512 + j];
#pragma unroll
                for (int o2 = 0; o2 < 64; ++o2) s += ps[r * 1024 + o2 * 16 + j];
                const int trow = t0 + rb * 8 + r;
                const float yv = y_g[((size_t)b * YDIM + j) * TT + trow];
                const float d = s - yv;
                lossreg += d * d;
            }
            // loop-top barrier closes this batch
        }
    }
    __syncthreads();
#pragma unroll
    for (int off = 32; off > 0; off >>= 1) lossreg += __shfl_down(lossreg, off, 64);
    if ((T & 63) == 0) red[T >> 6] = lossreg;
    __syncthreads();
    if (T == 0) {
        float s = 0.f;
#pragma unroll
        for (int i = 0; i < 8; ++i) s += red[i];
        atomicAdd(out, s);
    }
}

__global__ void zero_out_kernel(float* o) { o[0] = 0.f; }

extern "C" void kernel_launch(void* const* d_in, const int* in_sizes, int n_in,
                              void* d_out, int out_size, void* d_ws, size_t ws_size,
                              hipStream_t stream)
{
    (void)in_sizes; (void)n_in; (void)out_size;
    const float* u    = (const float*)d_in[0];
    const float* y    = (const float*)d_in[1];
    const float* h0   = (const float*)d_in[2];
    const float* puw1 = (const float*)d_in[3];
    const float* pub1 = (const float*)d_in[4];
    const float* puw2 = (const float*)d_in[5];
    const float* pub2 = (const float*)d_in[6];
    const float* dw1  = (const float*)d_in[7];
    const float* db1  = (const float*)d_in[8];
    const float* dw2  = (const float*)d_in[9];
    const float* db2  = (const float*)d_in[10];
    const float* xw   = (const float*)d_in[11];
    const float* xbi  = (const float*)d_in[12];
    const float* pxw1 = (const float*)d_in[13];
    const float* pxb1 = (const float*)d_in[14];
    const float* pxw2 = (const float*)d_in[15];
    const float* pxb2 = (const float*)d_in[16];
    const float* mw1  = (const float*)d_in[17];
    const float* mb1  = (const float*)d_in[18];
    const float* mw2  = (const float*)d_in[19];
    const float* mb2  = (const float*)d_in[20];
    const float* gwih = (const float*)d_in[21];
    const float* gwhh = (const float*)d_in[22];

    const size_t extra = (3 * 16384 + 128) * sizeof(float);   // A, W_C, b_C
    const size_t per_sample = (size_t)TT * HH * 2 * 2;        // pu + hlast (bf16)
    int C = BB;
    while (C > 1 && (size_t)C * per_sample + extra > ws_size) C >>= 1;
    bf16* puB = (bf16*)d_ws;
    bf16* hlB = puB + (size_t)C * TT * HH;
    float* Aw = (float*)((char*)d_ws + (size_t)C * per_sample);
    float* wC = Aw + 16384;
    float* bC = wC + 16384;

    zero_out_kernel<<<1, 1, 0, stream>>>((float*)d_out);
    pre1_kernel<<<1, 512, 0, stream>>>(pxw1, xw, Aw);
    pre2_kernel<<<33, 512, 0, stream>>>(Aw, dw2, db2, pxw1, xbi, pxb1, wC, bC);
    for (int s0 = 0; s0 < BB; s0 += C) {
        phi_u_kernel<<<512, 512, 0, stream>>>(u, puw1, pub1, puw2, pub2, puB, s0, C * TT);
        gru_fused_kernel<<<C, 512, 0, stream>>>(puB, gwih, gwhh, h0, hlB, s0);
        head_kernel<<<512, 512, 0, stream>>>(puB, hlB, y,
                                             dw1, db1, wC, bC,
                                             pxw2, pxb2, mw1, mb1, mw2, mb2,
                                             (float*)d_out, s0, C * TT);
    }
}

// Round 20
// 4828.209 us; speedup vs baseline: 1.4870x; 1.4870x over previous
//
#include <hip/hip_runtime.h>
#include <hip/hip_bf16.h>

#define TT 2048
#define BB 256
#define HH 128
#define UDIM 16
#define YDIM 16
#define ZDIM 32
#define H3 384

typedef __hip_bfloat16 bf16;
typedef _Float16 half2v __attribute__((ext_vector_type(2)));

constexpr int clog2(int x) { return x <= 1 ? 0 : 1 + clog2(x >> 1); }

// ---------------------------------------------------------------------------
// f32 register-weight linear stage (phi_u only).
// ---------------------------------------------------------------------------
template <int M_, int K_, int O_, bool RELU_>
__device__ __forceinline__ void rstage(const float* __restrict__ wfrag,
                                       const float* __restrict__ xin, int XS,
                                       float* __restrict__ ps,
                                       const float* __restrict__ bias,
                                       float* __restrict__ outb)
{
    constexpr int F = K_ / O_;
    const int T = threadIdx.x;
    const int jb = T & (M_ / 2 - 1);
    const int o  = T >> clog2(M_ / 2);
#pragma unroll
    for (int r = 0; r < 8; ++r) {
        float a0 = 0.f, a1 = 0.f;
#pragma unroll
        for (int g = 0; g < F; g += 4) {
            const float4 xv = *reinterpret_cast<const float4*>(&xin[r * XS + o * F + g]);
            a0 += xv.x * wfrag[g]     + xv.y * wfrag[g + 1]
                + xv.z * wfrag[g + 2] + xv.w * wfrag[g + 3];
            a1 += xv.x * wfrag[F + g]     + xv.y * wfrag[F + g + 1]
                + xv.z * wfrag[F + g + 2] + xv.w * wfrag[F + g + 3];
        }
        ps[r * 1024 + o * M_ + jb]           = a0;
        ps[r * 1024 + o * M_ + jb + M_ / 2]  = a1;
    }
    __syncthreads();
    for (int oi = T; oi < 8 * M_; oi += 512) {
        const int r = oi >> clog2(M_);
        const int j = oi & (M_ - 1);
        float s = bias[j];
#pragma unroll
        for (int o2 = 0; o2 < O_; ++o2) s += ps[r * 1024 + o2 * M_ + j];
        if (RELU_) s = fmaxf(s, 0.f);
        outb[r * M_ + j] = s;
    }
    __syncthreads();
}

template <int M_, int K_, int O_>
__device__ __forceinline__ void loadw(float* __restrict__ wfrag, const float* __restrict__ Wg)
{
    constexpr int F = K_ / O_;
    const int T = threadIdx.x;
    const int jb = T & (M_ / 2 - 1);
    const int o  = T >> clog2(M_ / 2);
#pragma unroll
    for (int h = 0; h < 2; ++h)
#pragma unroll
        for (int g = 0; g < F; g += 4)
            *reinterpret_cast<float4*>(&wfrag[h * F + g]) =
                *reinterpret_cast<const float4*>(&Wg[(jb + h * (M_ / 2)) * K_ + o * F + g]);
}

// f16 variants (head): wfrag = F half2 (2 rows x F/2), xin f16 LDS, XS in halves.
template <int M_, int K_, int O_>
__device__ __forceinline__ void loadw_h(half2v* __restrict__ wfrag, const float* __restrict__ Wg)
{
    constexpr int F = K_ / O_;
    const int T = threadIdx.x;
    const int jb = T & (M_ / 2 - 1);
    const int o  = T >> clog2(M_ / 2);
#pragma unroll
    for (int h = 0; h < 2; ++h)
#pragma unroll
        for (int g = 0; g < F / 2; ++g) {
            const float* s = &Wg[(jb + h * (M_ / 2)) * K_ + o * F + 2 * g];
            half2v v; v.x = (_Float16)s[0]; v.y = (_Float16)s[1];
            wfrag[h * (F / 2) + g] = v;
        }
}

template <int M_, int K_, int O_, bool RELU_>
__device__ __forceinline__ void rstage_h(const half2v* __restrict__ wfrag,
                                         const _Float16* __restrict__ xin, int XS,
                                         float* __restrict__ ps,
                                         const float* __restrict__ bias,
                                         _Float16* __restrict__ outb)
{
    constexpr int F = K_ / O_;
    constexpr int FH = F / 2;
    const int T = threadIdx.x;
    const int jb = T & (M_ / 2 - 1);
    const int o  = T >> clog2(M_ / 2);
#pragma unroll
    for (int r = 0; r < 8; ++r) {
        float a0 = 0.f, a1 = 0.f;
        const half2v* xv = reinterpret_cast<const half2v*>(xin + r * XS + o * F);
        if constexpr (FH >= 4) {
#pragma unroll
            for (int g4 = 0; g4 < FH / 4; ++g4) {
                half2v xt[4];
                *reinterpret_cast<float4*>(xt) = reinterpret_cast<const float4*>(xv)[g4];
#pragma unroll
                for (int e = 0; e < 4; ++e) {
                    a0 = __builtin_amdgcn_fdot2(xt[e], wfrag[g4 * 4 + e], a0, false);
                    a1 = __builtin_amdgcn_fdot2(xt[e], wfrag[FH + g4 * 4 + e], a1, false);
                }
            }
        } else {   // FH == 2
            half2v xt[2];
            *reinterpret_cast<float2*>(xt) = *reinterpret_cast<const float2*>(xv);
            a0 = __builtin_amdgcn_fdot2(xt[0], wfrag[0], a0, false);
            a0 = __builtin_amdgcn_fdot2(xt[1], wfrag[1], a0, false);
            a1 = __builtin_amdgcn_fdot2(xt[0], wfrag[FH], a1, false);
            a1 = __builtin_amdgcn_fdot2(xt[1], wfrag[FH + 1], a1, false);
        }
        ps[r * 1024 + o * M_ + jb]           = a0;
        ps[r * 1024 + o * M_ + jb + M_ / 2]  = a1;
    }
    __syncthreads();
    for (int oi = T; oi < 8 * M_; oi += 512) {
        const int r = oi >> clog2(M_);
        const int j = oi & (M_ - 1);
        float s = bias[j];
#pragma unroll
        for (int o2 = 0; o2 < O_; ++o2) s += ps[r * 1024 + o2 * M_ + j];
        if (RELU_) s = fmaxf(s, 0.f);
        outb[r * M_ + j] = (_Float16)s;
    }
    __syncthreads();
}

// ---------------------------------------------------------------------------
// phi_u: register weights, persistent 512 blocks (unchanged).
// ---------------------------------------------------------------------------
__global__ __launch_bounds__(512, 2) void phi_u_kernel(
    const float* __restrict__ u, const float* __restrict__ w1, const float* __restrict__ b1,
    const float* __restrict__ w2, const float* __restrict__ b2,
    bf16* __restrict__ pu, int s0, int nrows)
{
    __shared__ __align__(16) float ps[8192];
    __shared__ __align__(16) float xc[8 * 16];
    __shared__ __align__(16) float bP[8 * 128];
    __shared__ __align__(16) float bias_l[256];
    const int T = threadIdx.x;
    if (T < 128) { bias_l[T] = b1[T]; bias_l[128 + T] = b2[T]; }
    const int jb = T & 63, o = T >> 6;
    float wa[4];
    wa[0] = w1[jb * 16 + o * 2];        wa[1] = w1[jb * 16 + o * 2 + 1];
    wa[2] = w1[(jb + 64) * 16 + o * 2]; wa[3] = w1[(jb + 64) * 16 + o * 2 + 1];
    float wb[32]; loadw<128, 128, 8>(wb, w2);
    __syncthreads();

    for (int tile = blockIdx.x; tile < nrows / 32; tile += gridDim.x) {
        const int n0 = tile * 32;
        const int b  = s0 + (n0 >> 11);
        const int t0 = n0 & (TT - 1);
#pragma unroll 1
        for (int rb = 0; rb < 4; ++rb) {
            if (T < 128) {
                const int r = T & 7, c = T >> 3;
                xc[r * 16 + c] = u[((size_t)b * UDIM + c) * TT + t0 + rb * 8 + r];
            }
            __syncthreads();
#pragma unroll
            for (int r = 0; r < 8; ++r) {
                const float x0 = xc[r * 16 + o * 2], x1 = xc[r * 16 + o * 2 + 1];
                ps[r * 1024 + o * 128 + jb]      = x0 * wa[0] + x1 * wa[1];
                ps[r * 1024 + o * 128 + jb + 64] = x0 * wa[2] + x1 * wa[3];
            }
            __syncthreads();
            for (int oi = T; oi < 8 * 128; oi += 512) {
                const int r = oi >> 7, j = oi & 127;
                float s = bias_l[j];
#pragma unroll
                for (int o2 = 0; o2 < 8; ++o2) s += ps[r * 1024 + o2 * 128 + j];
                bP[r * 128 + j] = fmaxf(s, 0.f);
            }
            __syncthreads();
            rstage<128, 128, 8, false>(wb, bP, 128, ps, bias_l + 128, bP);
            const int row0 = n0 + rb * 8;
            for (int oi = T; oi < 8 * 128; oi += 512) {
                const int r = oi >> 7, j = oi & 127;
                pu[(size_t)(row0 + r) * HH + j] = __float2bfloat16(bP[r * 128 + j]);
            }
            __syncthreads();
        }
    }
}

// ---------------------------------------------------------------------------
// Fused 2-layer GRU, 512 threads (round-12 proven config).
// ---------------------------------------------------------------------------
__device__ __forceinline__ void gmv(const half2v w[6][16], const _Float16* __restrict__ vb,
                                    int o, float* __restrict__ psL, int psb)
{
    const half2v* vec2 = reinterpret_cast<const half2v*>(vb) + o * 16;
    float a0 = 0.f, a1 = 0.f, a2 = 0.f, a3 = 0.f, a4 = 0.f, a5 = 0.f;
#pragma unroll
    for (int k4 = 0; k4 < 4; ++k4) {
        half2v xt[4];
        *reinterpret_cast<float4*>(xt) = reinterpret_cast<const float4*>(vec2)[k4];
#pragma unroll
        for (int e = 0; e < 4; ++e) {
            const int k = k4 * 4 + e;
            a0 = __builtin_amdgcn_fdot2(xt[e], w[0][k], a0, false);
            a1 = __builtin_amdgcn_fdot2(xt[e], w[1][k], a1, false);
            a2 = __builtin_amdgcn_fdot2(xt[e], w[2][k], a2, false);
            a3 = __builtin_amdgcn_fdot2(xt[e], w[3][k], a3, false);
            a4 = __builtin_amdgcn_fdot2(xt[e], w[4][k], a4, false);
            a5 = __builtin_amdgcn_fdot2(xt[e], w[5][k], a5, false);
        }
    }
    psL[psb]       = a0; psL[psb + 64]  = a1; psL[psb + 128] = a2;
    psL[psb + 192] = a3; psL[psb + 256] = a4; psL[psb + 320] = a5;
}

__global__ __launch_bounds__(512, 2) void gru_fused_kernel(
    const bf16* __restrict__ pu_in,   // (C*T, H)
    const float* __restrict__ wih,    // (L, 3H, H)
    const float* __restrict__ whh,    // (L, 3H, H)
    const float* __restrict__ h0_g,   // (L, B, H)
    bf16* __restrict__ hlast,         // (C*T, H)
    int s0)
{
    const int t = threadIdx.x;
    __shared__ __align__(16) _Float16 x0h[HH];
    __shared__ __align__(16) _Float16 x1h[2][HH];
    __shared__ __align__(16) _Float16 h0h[HH];
    __shared__ __align__(16) _Float16 h1h[HH];
    __shared__ __align__(16) float ps[2 * 3072];

    const int g = t >> 6;             // wave-uniform
    const int m = g >> 2, o = g & 3;
    const int u = t & 63;
    const float* WbaseA = ((m == 0) ? wih : whh);
    const float* WbaseB = WbaseA + (size_t)H3 * HH;
    half2v wA[6][16], wB[6][16];
#pragma unroll
    for (int i = 0; i < 6; ++i) {
        const float* sA = &WbaseA[(u + 64 * i) * HH + o * 32];
        const float* sB = &WbaseB[(u + 64 * i) * HH + o * 32];
#pragma unroll
        for (int k = 0; k < 16; ++k) {
            half2v v; v.x = (_Float16)sA[2 * k]; v.y = (_Float16)sA[2 * k + 1];
            wA[i][k] = v;
            half2v w2; w2.x = (_Float16)sB[2 * k]; w2.y = (_Float16)sB[2 * k + 1];
            wB[i][k] = w2;
        }
    }
    float* psA = ps;
    float* psB = ps + 3072;
    const int psb = o * 768 + m * 384 + u;

    const bf16* xb = pu_in + (size_t)blockIdx.x * TT * HH;
    bf16* ob = hlast + (size_t)blockIdx.x * TT * HH;

    float hreg = 0.f;                 // t<128: L0 state; t in [128,256): L1 state
    if (t < HH) {
        hreg = h0_g[(size_t)(s0 + blockIdx.x) * HH + t];
        h0h[t] = (_Float16)hreg;
        x0h[t] = (_Float16)__bfloat162float(xb[t]);
    } else if (t < 2 * HH) {
        const int j = t - HH;
        hreg = h0_g[((size_t)BB + s0 + blockIdx.x) * HH + j];
        h1h[j] = (_Float16)hreg;
    }
    __syncthreads();

#pragma unroll 1
    for (int i = 0; i <= TT; ++i) {
        float xnext = 0.f;
        if (t < HH && i + 1 < TT)
            xnext = __bfloat162float(xb[(size_t)(i + 1) * HH + t]);   // prefetch for L0
        if (i < TT)  gmv(wA, (m == 0) ? x0h : h0h, o, psA, psb);
        if (i >= 1)  gmv(wB, (m == 0) ? x1h[(i + 1) & 1] : h1h, o, psB, psb);
        __syncthreads();   // ps ready; all LDS vec reads done
        if (t < HH) {
            if (i < TT) {
                const int j = t;
                float gir = 0.f, giz = 0.f, gin = 0.f, ghr = 0.f, ghz = 0.f, ghn = 0.f;
#pragma unroll
                for (int o2 = 0; o2 < 4; ++o2) {
                    const float* pp = psA + o2 * 768;
                    gir += pp[j];        giz += pp[128 + j]; gin += pp[256 + j];
                    ghr += pp[384 + j];  ghz += pp[512 + j]; ghn += pp[640 + j];
                }
                const float rg = 1.f / (1.f + __expf(-(gir + ghr)));
                const float zg = 1.f / (1.f + __expf(-(giz + ghz)));
                const float narg = gin + rg * ghn;
                const float e2 = __expf(2.f * fabsf(narg));
                float ng = 1.f - 2.f / (e2 + 1.f);
                ng = (narg < 0.f) ? -ng : ng;
                const float hn = (1.f - zg) * ng + zg * hreg;
                h0h[j] = (_Float16)hn;
                x1h[i & 1][j] = (_Float16)hn;   // L1 input for step i
                x0h[j] = (_Float16)xnext;
                hreg = hn;
            }
        } else if (t < 2 * HH) {
            if (i >= 1) {
                const int j = t - HH;
                float gir = 0.f, giz = 0.f, gin = 0.f, ghr = 0.f, ghz = 0.f, ghn = 0.f;
#pragma unroll
                for (int o2 = 0; o2 < 4; ++o2) {
                    const float* pp = psB + o2 * 768;
                    gir += pp[j];        giz += pp[128 + j]; gin += pp[256 + j];
                    ghr += pp[384 + j];  ghz += pp[512 + j]; ghn += pp[640 + j];
                }
                const float rg = 1.f / (1.f + __expf(-(gir + ghr)));
                const float zg = 1.f / (1.f + __expf(-(giz + ghz)));
                const float narg = gin + rg * ghn;
                const float e2 = __expf(2.f * fabsf(narg));
                float ng = 1.f - 2.f / (e2 + 1.f);
                ng = (narg < 0.f) ? -ng : ng;
                ob[(size_t)(i - 1) * HH + j] = __float2bfloat16(hreg);  // pre-update
                const float hn = (1.f - zg) * ng + zg * hreg;
                h1h[j] = (_Float16)hn;
                hreg = hn;
            }
        }
        __syncthreads();   // h/x updated for next iteration
    }
}

// ---------------------------------------------------------------------------
// head v6: 5 composed stages, with W_C = (pxw1·xw)·dw2 and
// b_C = pxb1 + pxw1·(xw·db2 + xb) computed ONCE per block at startup using
// the ps LDS array as staging (B = xw·dw2 in ps[0..4095], c2 in ps[4096..]).
// No extra workspace -> C stays 256 (single chunk).
// ---------------------------------------------------------------------------
__device__ __forceinline__ void stage_xc_h(_Float16* __restrict__ xc,
                                           const bf16* __restrict__ pu,
                                           const bf16* __restrict__ hl,
                                           int n0, int rb)
{
    const int T = threadIdx.x;
    const int base = n0 + rb * 8;
#pragma unroll
    for (int i = 0; i < 4; ++i) {
        const int idx = T + i * 512;
        const int r = idx >> 8, k = idx & 255;
        const size_t row = (size_t)(base + r);
        xc[r * 256 + k] = (_Float16)((k < 128) ? __bfloat162float(pu[row * HH + k])
                                               : __bfloat162float(hl[row * HH + (k - 128)]));
    }
}

__global__ __launch_bounds__(512, 2) void head_kernel(
    const bf16* __restrict__ pu, const bf16* __restrict__ hlast, const float* __restrict__ y_g,
    const float* __restrict__ dw1, const float* __restrict__ db1,
    const float* __restrict__ dw2, const float* __restrict__ db2,
    const float* __restrict__ xw, const float* __restrict__ xb,
    const float* __restrict__ pxw1, const float* __restrict__ pxb1,
    const float* __restrict__ pxw2, const float* __restrict__ pxb2,
    const float* __restrict__ mw1, const float* __restrict__ mb1,
    const float* __restrict__ mw2, const float* __restrict__ mb2,
    float* __restrict__ out, int s0, int nrows)
{
    __shared__ __align__(16) float ps[8192];
    __shared__ __align__(16) _Float16 xc[8 * 256];
    __shared__ __align__(16) _Float16 bP[8 * 128];
    __shared__ __align__(16) _Float16 bQ[8 * 128];
    __shared__ __align__(16) float bias_l[528];
    __shared__ float red[8];
    const int T = threadIdx.x;

    if (T < 128) bias_l[T]       = db1[T];
    if (T < 128) bias_l[256 + T] = pxb2[T];
    if (T < 128) bias_l[384 + T] = mb1[T];
    if (T < 16)  bias_l[512 + T] = mb2[T];

    // ---- one-time composite-weight build: B = xw·dw2 -> ps; c2 -> ps[4096..]
    for (int idx = T; idx < 4096; idx += 512) {
        const int z = idx >> 7, k = idx & 127;
        float s = 0.f;
        for (int m2 = 0; m2 < 128; ++m2) s += xw[z * 128 + m2] * dw2[m2 * 128 + k];
        ps[idx] = s;
    }
    if (T < 32) {
        float c = xb[T];
        for (int m2 = 0; m2 < 128; ++m2) c += xw[T * 128 + m2] * db2[m2];
        ps[4096 + T] = c;
    }
    __syncthreads();
    half2v wc[16];
    {
        const int jbw = T & 63, ow = T >> 6;
#pragma unroll
        for (int h = 0; h < 2; ++h) {
            const int j = jbw + h * 64;
#pragma unroll
            for (int gg = 0; gg < 8; ++gg) {
                const int k0 = ow * 16 + 2 * gg;
                float s0 = 0.f, s1 = 0.f;
#pragma unroll
                for (int z = 0; z < 32; ++z) {
                    const float p = pxw1[j * 32 + z];
                    s0 += p * ps[z * 128 + k0];
                    s1 += p * ps[z * 128 + k0 + 1];
                }
                half2v v; v.x = (_Float16)s0; v.y = (_Float16)s1;
                wc[h * 8 + gg] = v;
            }
        }
    }
    if (T < 128) {
        float s = pxb1[T];
#pragma unroll
        for (int z = 0; z < 32; ++z) s += pxw1[T * 32 + z] * ps[4096 + z];
        bias_l[128 + T] = s;
    }

    half2v w1[32]; loadw_h<128, 256, 8 >(w1, dw1);
    half2v w5[16]; loadw_h<128, 128, 8 >(w5, pxw2);
    half2v w6[16]; loadw_h<128, 128, 8 >(w6, mw1);
    const int jb7 = T & 7, o7 = T >> 3;   // S7: M=16,K=128,O=64,F=2
    half2v w7a, w7b;
    w7a.x = (_Float16)mw2[jb7 * 128 + 2 * o7];
    w7a.y = (_Float16)mw2[jb7 * 128 + 2 * o7 + 1];
    w7b.x = (_Float16)mw2[(jb7 + 8) * 128 + 2 * o7];
    w7b.y = (_Float16)mw2[(jb7 + 8) * 128 + 2 * o7 + 1];

    float lossreg = 0.f;

    for (int tile = blockIdx.x; tile < nrows / 32; tile += gridDim.x) {
        const int n0 = tile * 32;
        const int b  = s0 + (n0 >> 11);
        const int t0 = n0 & (TT - 1);
        stage_xc_h(xc, pu, hlast, n0, 0);
#pragma unroll 1
        for (int rb = 0; rb < 4; ++rb) {
            __syncthreads();   // xc ready; ps free (staging done / prev batch)
            rstage_h<128, 256, 8, true >(w1, xc, 256, ps, bias_l + 0,   bP);  // dynn hid
            rstage_h<128, 128, 8, true >(wc, bP, 128, ps, bias_l + 128, bQ);  // composite
            rstage_h<128, 128, 8, false>(w5, bQ, 128, ps, bias_l + 256, bP);  // px
            rstage_h<128, 128, 8, true >(w6, bP, 128, ps, bias_l + 384, bQ);  // menn hid
            // S7 partials (dot2) + prefetch next batch's xc
#pragma unroll
            for (int r = 0; r < 8; ++r) {
                const half2v xv = *reinterpret_cast<const half2v*>(&bQ[r * 128 + 2 * o7]);
                ps[r * 1024 + o7 * 16 + jb7]     = __builtin_amdgcn_fdot2(xv, w7a, 0.f, false);
                ps[r * 1024 + o7 * 16 + jb7 + 8] = __builtin_amdgcn_fdot2(xv, w7b, 0.f, false);
            }
            if (rb < 3) stage_xc_h(xc, pu, hlast, n0, rb + 1);
            __syncthreads();
            if (T < 128) {
                const int r = T >> 4, j = T & 15;
                float s = bias_l[512 + j];
#pragma unroll
                for (int o2 = 0; o2 < 64; ++o2) s += ps[r * 1024 + o2 * 16 + j];
                const int trow = t0 + rb * 8 + r;
                const float yv = y_g[((size_t)b * YDIM + j) * TT + trow];
                const float d = s - yv;
                lossreg += d * d;
            }
            // loop-top barrier closes this batch
        }
    }
    __syncthreads();
#pragma unroll
    for (int off = 32; off > 0; off >>= 1) lossreg += __shfl_down(lossreg, off, 64);
    if ((T & 63) == 0) red[T >> 6] = lossreg;
    __syncthreads();
    if (T == 0) {
        float s = 0.f;
#pragma unroll
        for (int i = 0; i < 8; ++i) s += red[i];
        atomicAdd(out, s);
    }
}

__global__ void zero_out_kernel(float* o) { o[0] = 0.f; }

extern "C" void kernel_launch(void* const* d_in, const int* in_sizes, int n_in,
                              void* d_out, int out_size, void* d_ws, size_t ws_size,
                              hipStream_t stream)
{
    (void)in_sizes; (void)n_in; (void)out_size;
    const float* u    = (const float*)d_in[0];
    const float* y    = (const float*)d_in[1];
    const float* h0   = (const float*)d_in[2];
    const float* puw1 = (const float*)d_in[3];
    const float* pub1 = (const float*)d_in[4];
    const float* puw2 = (const float*)d_in[5];
    const float* pub2 = (const float*)d_in[6];
    const float* dw1  = (const float*)d_in[7];
    const float* db1  = (const float*)d_in[8];
    const float* dw2  = (const float*)d_in[9];
    const float* db2  = (const float*)d_in[10];
    const float* xw   = (const float*)d_in[11];
    const float* xbi  = (const float*)d_in[12];
    const float* pxw1 = (const float*)d_in[13];
    const float* pxb1 = (const float*)d_in[14];
    const float* pxw2 = (const float*)d_in[15];
    const float* pxb2 = (const float*)d_in[16];
    const float* mw1  = (const float*)d_in[17];
    const float* mb1  = (const float*)d_in[18];
    const float* mw2  = (const float*)d_in[19];
    const float* mb2  = (const float*)d_in[20];
    const float* gwih = (const float*)d_in[21];
    const float* gwhh = (const float*)d_in[22];

    const size_t per_sample = (size_t)TT * HH * 2 * 2;   // pu + hlast (bf16)
    int C = BB;
    while (C > 1 && (size_t)C * per_sample > ws_size) C >>= 1;
    bf16* puB = (bf16*)d_ws;
    bf16* hlB = puB + (size_t)C * TT * HH;

    zero_out_kernel<<<1, 1, 0, stream>>>((float*)d_out);
    for (int s0 = 0; s0 < BB; s0 += C) {
        phi_u_kernel<<<512, 512, 0, stream>>>(u, puw1, pub1, puw2, pub2, puB, s0, C * TT);
        gru_fused_kernel<<<C, 512, 0, stream>>>(puB, gwih, gwhh, h0, hlB, s0);
        head_kernel<<<512, 512, 0, stream>>>(puB, hlB, y,
                                             dw1, db1, dw2, db2, xw, xbi,
                                             pxw1, pxb1, pxw2, pxb2,
                                             mw1, mb1, mw2, mb2,
                                             (float*)d_out, s0, C * TT);
    }
}